// Round 19
// baseline (300.774 us; speedup 1.0000x reference)
//
#include <hip/hip_runtime.h>
#include <hip/hip_bf16.h>

#define NPIX 16384
#define NVOC 8192
#define CHUNK 32

typedef short short8v __attribute__((ext_vector_type(8)));
typedef float floatx4 __attribute__((ext_vector_type(4)));

// ---- ws layout (bytes) ----
#define WS_ZEBF   0u          // 16384*256 bf16 = 8388608 (dead after k_gemm)
#define WS_BLIST  0u          // 128*16384 i32 = 8388608 (alias, post-gemm)
#define WS_PART   0u          // 256 f32 (alias, post-rescore; blist dead)
#define WS_CBBF   8388608u    // 8192*256 bf16 = 4194304 (dead after k_gemm)
#define WS_PK     8388608u    // 16384 u64 = 131072 (alias, post-gemm)
#define WS_TAU    8519680u    // 16384 f32 = 65536 (alias, post-gemm)
#define WS_ZEF    12582912u   // 16384*256 f32 = 16777216
#define WS_MIN    29360128u   // 128*16384 f32 = 8388608 ; cbsw after compact
#define WS_BN     37748736u   // 8192 f32
#define WS_AN     37781504u   // 16384 f32
#define WS_BCNT   37847040u   // 128 i32 (pad to 512)
#define WS_BMAXU  37847552u   // 1 u32
#define WS_QCNT   37847556u   // 1 i32
#define WS_QUEUE  37847808u   // 131072 i32 = 524288

__device__ __forceinline__ short f2bf(float v) {
  __bf16 h = (__bf16)v;
  return __builtin_bit_cast(short, h);
}

__device__ __forceinline__ unsigned long long packdj(float d, int j) {
  return ((unsigned long long)__float_as_uint(d) << 32) | (unsigned int)j;
}

__device__ __forceinline__ void gll16(const void* g, void* l) {
  __builtin_amdgcn_global_load_lds(
      (const __attribute__((address_space(1))) void*)g,
      (__attribute__((address_space(3))) void*)l, 16, 0, 0);
}

// numpy pairwise-sum of 128 squares
__device__ __forceinline__ float np_pairwise128_sq(const float* x, int stride) {
  float r[8];
#pragma unroll
  for (int j = 0; j < 8; ++j) {
    float v = x[j * stride];
    r[j] = __fmul_rn(v, v);
  }
#pragma unroll
  for (int i = 1; i < 16; ++i) {
#pragma unroll
    for (int j = 0; j < 8; ++j) {
      float v = x[(i * 8 + j) * stride];
      r[j] = __fadd_rn(r[j], __fmul_rn(v, v));
    }
  }
  return __fadd_rn(__fadd_rn(__fadd_rn(r[0], r[1]), __fadd_rn(r[2], r[3])),
                   __fadd_rn(__fadd_rn(r[4], r[5]), __fadd_rn(r[6], r[7])));
}

// ze -> zebf (MFMA-fragment order) + zef + an; inits bmaxu/qcnt.
__global__ __launch_bounds__(256) void k_cvt_ze(const float* __restrict__ ze,
                                                short* __restrict__ zebff,
                                                float* __restrict__ zef,
                                                float* __restrict__ an,
                                                unsigned* __restrict__ bmaxu,
                                                int* __restrict__ qcnt) {
  __shared__ float t[64][132];
  int tid = threadIdx.x;
  if (blockIdx.x == 0 && tid == 0) {
    bmaxu[0] = 0u;
    qcnt[0] = 0;
  }
  int p0 = blockIdx.x * 64;
  int b = p0 >> 10, hw0 = p0 & 1023;
  const float* src = ze + (size_t)b * 262144 + hw0;
  float apart = 0.f;
  for (int half = 0; half < 2; ++half) {
    if (half) __syncthreads();
    {
      int hw = tid & 63, cq = tid >> 6;
#pragma unroll
      for (int i = 0; i < 32; ++i) {
        int cl = i * 4 + cq;
        t[hw][cl] = src[(size_t)(half * 128 + cl) * 1024 + hw];
      }
    }
    __syncthreads();
    {
      int r = tid >> 2, cg = tid & 3;
      float* fd = zef + (size_t)(p0 + r) * 256 + half * 128 + cg * 32;
#pragma unroll
      for (int s = 0; s < 8; ++s) {
        float4 v = *reinterpret_cast<const float4*>(&t[r][cg * 32 + s * 4]);
        *reinterpret_cast<float4*>(fd + s * 4) = v;
      }
    }
    {
      int pg_l = tid >> 6, l = tid & 63;
      size_t pg = (size_t)(p0 >> 4) + pg_l;
      int lr = l & 15, lg = l >> 4;
#pragma unroll
      for (int kl = 0; kl < 4; ++kl) {
        int ks = half * 4 + kl;
        short8v v8;
#pragma unroll
        for (int e = 0; e < 8; ++e)
          v8[e] = f2bf(t[pg_l * 16 + lr][kl * 32 + lg * 8 + e]);
        *reinterpret_cast<short8v*>(zebff + (pg * 8 + ks) * 512 + l * 8) = v8;
      }
    }
    if (tid < 64) {
      float a = np_pairwise128_sq(&t[tid][0], 1);
      apart = half ? __fadd_rn(apart, a) : a;
    }
  }
  if (tid < 64) an[p0 + tid] = apart;
}

// FUSED: cb -> bf16 in per-32-code-tile K-MAJOR layout + bn + bmax.
// Tile tt (32 codes), record rid = kc*32 + c2 at cbbft[tt*8192 + rid*8]:
// 8 bf16 of code tt*32+c2, k = kc*8..kc*8+7.
__global__ __launch_bounds__(256) void k_cvt_cb(const float* __restrict__ cb,
                                                short* __restrict__ cbbft,
                                                float* __restrict__ bn,
                                                unsigned* __restrict__ bmaxu) {
  __shared__ float rows[64][257];
  int tid = threadIdx.x;
  int j0 = blockIdx.x * 64;
  for (int r = 0; r < 64; ++r)
    rows[r][tid] = cb[(size_t)(j0 + r) * 256 + tid];
  __syncthreads();
  if (tid < 64) {
    float a = np_pairwise128_sq(&rows[tid][0], 1);
    float b2 = np_pairwise128_sq(&rows[tid][128], 1);
    float v = __fadd_rn(a, b2);
    bn[j0 + tid] = v;
    atomicMax(bmaxu, __float_as_uint(v));
  }
  short* dst = cbbft + (size_t)blockIdx.x * 16384;  // 2 tiles per block
#pragma unroll
  for (int s = 0; s < 8; ++s) {
    int id = tid + s * 256;      // 0..2047
    int th = id >> 10;           // tile half
    int rid = id & 1023;
    int kc = rid >> 5, c2 = rid & 31;
    short8v v;
#pragma unroll
    for (int e = 0; e < 8; ++e) v[e] = f2bf(rows[th * 32 + c2][kc * 8 + e]);
    *reinterpret_cast<short8v*>(dst + id * 8) = v;
  }
}

// Swapped-operand bf16 MFMA GEMM, 32-code tiles, 4 blocks/CU (LDS 34KB).
// Grid 1024 = 64 px-chunks (256px) x 16 col-segments (512 cols = 16 tiles).
// Per-iter: stage next 16KB tile, 2cf x 4pf x 8ks MFMA, in-lane colmin;
// pair-combine two 32-code tile mins -> one 64-code wsmin store (1/lane).
// vmcnt exact: (0) after even tiles (covered by compute), (1) after odd.
// t_hat chains instruction-identical to R18 -> wsmin bit-identical.
__global__ __launch_bounds__(256, 4) void k_gemm(const short* __restrict__ zebff,
                                                 const short* __restrict__ cbbft,
                                                 const float* __restrict__ bn,
                                                 float* __restrict__ wsmin) {
  __shared__ short lds[16384];  // 2 x 8192 shorts (16KB each)
  __shared__ float bnlds[512];  // segment bn
  int tid = threadIdx.x;
  int lane = tid & 63, w = tid >> 6;
  int g = lane >> 4, r16 = lane & 15;
  int seg = blockIdx.x & 15, chunk = blockIdx.x >> 4;
  int p0 = chunk * 256;
  int ncol0 = seg * 512;

  short8v pix[4][8];
  {
    const short* base = zebff + ((size_t)(p0 >> 4) + w * 4) * 4096 + lane * 8;
#pragma unroll
    for (int pf = 0; pf < 4; ++pf)
#pragma unroll
      for (int ks = 0; ks < 8; ++ks)
        pix[pf][ks] =
            *reinterpret_cast<const short8v*>(base + pf * 4096 + ks * 512);
  }
  if (tid < 128) gll16(bn + ncol0 + tid * 4, &bnlds[tid * 4]);

#define STAGE(t, boff)                                                         \
  {                                                                            \
    const short* src_ = cbbft + (size_t)(seg * 16 + (t)) * 8192;               \
    _Pragma("unroll") for (int s = 0; s < 4; ++s) {                            \
      int cid_ = tid + s * 256;                                                \
      gll16(src_ + cid_ * 8, &lds[(boff) + cid_ * 8]);                         \
    }                                                                          \
  }
  STAGE(0, 0)
  asm volatile("s_waitcnt vmcnt(0)" ::: "memory");
  __builtin_amdgcn_s_barrier();

  float* wbase = wsmin + (size_t)(seg * 8) * NPIX + p0 + w * 64 + g * 16 + r16;
  float pminPrev[4];

  for (int t = 0; t < 16; ++t) {
    int bA = (t & 1) * 8192;
    int bC = bA ^ 8192;
    if (t < 15) STAGE(t + 1, bC)
    float4 bnv[2];
#pragma unroll
    for (int cf = 0; cf < 2; ++cf)
      bnv[cf] =
          *reinterpret_cast<const float4*>(&bnlds[t * 32 + cf * 16 + g * 4]);
    floatx4 acc[2][4];
#pragma unroll
    for (int cf = 0; cf < 2; ++cf)
#pragma unroll
      for (int pf = 0; pf < 4; ++pf) acc[cf][pf] = floatx4{0.f, 0.f, 0.f, 0.f};
    __builtin_amdgcn_s_setprio(1);
#pragma unroll
    for (int ks = 0; ks < 8; ++ks) {  // k-ascending: bit-identical chains
      short8v cfr[2];
#pragma unroll
      for (int cf = 0; cf < 2; ++cf)
        cfr[cf] = *reinterpret_cast<const short8v*>(
            &lds[bA + (((ks * 4 + g) * 32) + cf * 16 + r16) * 8]);
#pragma unroll
      for (int cf = 0; cf < 2; ++cf)
#pragma unroll
        for (int pf = 0; pf < 4; ++pf)
          acc[cf][pf] = __builtin_amdgcn_mfma_f32_16x16x32_bf16(
              cfr[cf], pix[pf][ks], acc[cf][pf], 0, 0, 0);
    }
    __builtin_amdgcn_s_setprio(0);
    float pmin[4];
#pragma unroll
    for (int pf = 0; pf < 4; ++pf) {
      float m_ = 3.4e38f;
#pragma unroll
      for (int cf = 0; cf < 2; ++cf) {
        m_ = fminf(m_, __builtin_fmaf(-2.0f, acc[cf][pf][0], bnv[cf].x));
        m_ = fminf(m_, __builtin_fmaf(-2.0f, acc[cf][pf][1], bnv[cf].y));
        m_ = fminf(m_, __builtin_fmaf(-2.0f, acc[cf][pf][2], bnv[cf].z));
        m_ = fminf(m_, __builtin_fmaf(-2.0f, acc[cf][pf][3], bnv[cf].w));
      }
      m_ = fminf(m_, __shfl_xor(m_, 16));
      m_ = fminf(m_, __shfl_xor(m_, 32));
      pmin[pf] = m_;
    }
    if (t & 1) {
      // pair-combine 32-code mins -> 64-code colblock row; 1 store per lane
      float v = fminf(pminPrev[0], pmin[0]);
      if (g == 1) v = fminf(pminPrev[1], pmin[1]);
      if (g == 2) v = fminf(pminPrev[2], pmin[2]);
      if (g == 3) v = fminf(pminPrev[3], pmin[3]);
      wbase[(size_t)(t >> 1) * NPIX] = v;
      asm volatile("s_waitcnt vmcnt(1)" ::: "memory");
    } else {
#pragma unroll
      for (int pf = 0; pf < 4; ++pf) pminPrev[pf] = pmin[pf];
      asm volatile("s_waitcnt vmcnt(0)" ::: "memory");
    }
    __builtin_amdgcn_s_barrier();
  }
#undef STAGE
}

// per-pixel global min over 128 colblocks -> tau; init pk.
__global__ __launch_bounds__(256) void k_tau(const float* __restrict__ wsmin,
                                             const float* __restrict__ an,
                                             const unsigned* __restrict__ bmaxu,
                                             float* __restrict__ tau,
                                             unsigned long long* __restrict__ pk) {
  __shared__ float sm[4][64];
  int tid = threadIdx.x;
  int px = tid & 63, q = tid >> 6;
  int p = blockIdx.x * 64 + px;
  float m0 = 3.4e38f, m1 = 3.4e38f, m2 = 3.4e38f, m3 = 3.4e38f;
#pragma unroll
  for (int i = 0; i < 8; ++i) {
    int c = q * 32 + i * 4;
    m0 = fminf(m0, wsmin[(size_t)c * NPIX + p]);
    m1 = fminf(m1, wsmin[(size_t)(c + 1) * NPIX + p]);
    m2 = fminf(m2, wsmin[(size_t)(c + 2) * NPIX + p]);
    m3 = fminf(m3, wsmin[(size_t)(c + 3) * NPIX + p]);
  }
  sm[q][px] = fminf(fminf(m0, m1), fminf(m2, m3));
  __syncthreads();
  if (tid < 64) {
    float m = fminf(fminf(sm[0][tid], sm[1][tid]), fminf(sm[2][tid], sm[3][tid]));
    float bmaxf = sqrtf(__uint_as_float(bmaxu[0]));
    tau[p] = m + 0.017f * sqrtf(an[p]) * bmaxf + 2e-4f;
    pk[p] = ~0ull;
  }
}

// per-colblock compaction; emits 32-code-group descriptors; fused cbsw build.
__global__ __launch_bounds__(256) void k_compact(const float* __restrict__ wsmin,
                                                 const float* __restrict__ tau,
                                                 const float* __restrict__ cb,
                                                 float* __restrict__ cbsw,
                                                 int* __restrict__ bcnt,
                                                 int* __restrict__ blist,
                                                 int* __restrict__ qcnt,
                                                 int* __restrict__ queue) {
  __shared__ int wbase[4];
  __shared__ int running;
  int c = blockIdx.x;
  const float* row = wsmin + (size_t)c * NPIX;
  int* dst = blist + (size_t)c * NPIX;
  int tid = threadIdx.x;
  int lane = tid & 63, wv = tid >> 6;
  if (tid == 0) running = 0;
  __syncthreads();
  for (int base = 0; base < NPIX; base += 256) {
    int p = base + tid;
    bool flag = row[p] <= tau[p];
    unsigned long long mask = __ballot(flag);
    int cnt = __popcll(mask);
    int pre = __popcll(mask & ((1ull << lane) - 1ull));
    if (lane == 0) wbase[wv] = cnt;
    __syncthreads();
    if (tid == 0) {
      int r = running;
#pragma unroll
      for (int w2 = 0; w2 < 4; ++w2) {
        int t = wbase[w2];
        wbase[w2] = r;
        r += t;
      }
      running = r;
    }
    __syncthreads();
    if (flag) dst[wbase[wv] + pre] = p;
    __syncthreads();
  }
  if (tid == 0) {
    int n = running;
    bcnt[c] = n;
    int nch = (n + CHUNK - 1) / CHUNK;
    if (nch > 0) {
      int q0 = atomicAdd(qcnt, nch * 2);
      for (int i = 0; i < nch; ++i) {
        queue[q0 + 2 * i] = (2 * c) | (i << 16);
        queue[q0 + 2 * i + 1] = (2 * c + 1) | (i << 16);
      }
    }
  }
  {
    const float4* cb4 = reinterpret_cast<const float4*>(cb);
    float4* dst4 = reinterpret_cast<float4*>(cbsw);
#pragma unroll
    for (int i = 0; i < 16; ++i) {
      int gid = tid + i * 256;
      int jj = 64 * c + (gid >> 6), u = gid & 63;
      dst4[(size_t)jj * 64 + u] = cb4[(size_t)jj * 64 + (u ^ (jj & 7))];
    }
  }
}

// queue-driven exact fp32 rescore v5: 2 blocks/CU. (unchanged)
__global__ __launch_bounds__(256, 2) void k_rescore_b(
    const float* __restrict__ zef, const float* __restrict__ cbsw,
    const float* __restrict__ an, const float* __restrict__ bn,
    const int* __restrict__ bcnt, const int* __restrict__ blist,
    const int* __restrict__ qcnt, const int* __restrict__ queue,
    unsigned long long* __restrict__ pk) {
  __shared__ float zl[32 * 256];
  __shared__ float cstf[32 * 256];
  __shared__ int pidx[32];
  __shared__ float apx[32];
  int tid = threadIdx.x;
  int lane = tid & 63, wv = tid >> 6;
  int code32 = lane & 31, half = lane >> 5;
  int nq = qcnt[0];
  for (int qi = blockIdx.x; qi < nq; qi += 512) {
    int e = queue[qi];
    int g = e & 0xffff, chunk = e >> 16;
    int c = g >> 1;
    int n = bcnt[c];
    int base = chunk * CHUNK;
    int cnt_here = min(CHUNK, n - base);
    __syncthreads();
#pragma unroll
    for (int i = 0; i < 8; ++i) {
      int px = wv * 8 + i;
      int idx = base + min(px, cnt_here - 1);
      int p = blist[(size_t)c * NPIX + idx];
      gll16(zef + (size_t)p * 256 + lane * 4, &zl[px * 256 + lane * 4]);
    }
#pragma unroll
    for (int i = 0; i < 8; ++i) {
      int r = wv * 8 + i;
      gll16(cbsw + (size_t)(g * 32 + r) * 256 + lane * 4,
            &cstf[r * 256 + lane * 4]);
    }
    if (tid < 32) {
      int idx = base + min(tid, cnt_here - 1);
      int p = blist[(size_t)c * NPIX + idx];
      pidx[tid] = p;
      apx[tid] = an[p];
    }
    asm volatile("s_waitcnt vmcnt(0)" ::: "memory");
    __syncthreads();
    int jg = g * 32 + code32;
    float bnj = bn[jg];
    int px0 = wv * 8 + half * 4;
    int sw = code32 & 7;
    const float* crow = &cstf[code32 * 256];
    float acc[4] = {0.f, 0.f, 0.f, 0.f};
#pragma unroll 8
    for (int k4 = 0; k4 < 64; ++k4) {
      float4 cv = *reinterpret_cast<const float4*>(&crow[(k4 ^ sw) << 2]);
#pragma unroll
      for (int i = 0; i < 4; ++i) {
        float4 zv =
            *reinterpret_cast<const float4*>(&zl[(px0 + i) * 256 + k4 * 4]);
        acc[i] = __builtin_fmaf(zv.x, cv.x, acc[i]);
        acc[i] = __builtin_fmaf(zv.y, cv.y, acc[i]);
        acc[i] = __builtin_fmaf(zv.z, cv.z, acc[i]);
        acc[i] = __builtin_fmaf(zv.w, cv.w, acc[i]);
      }
    }
#pragma unroll
    for (int i = 0; i < 4; ++i) {
      int px = px0 + i;
      float d = __fsub_rn(__fadd_rn(apx[px], bnj), 2.0f * acc[i]);
      unsigned long long q = packdj(d, jg);
#pragma unroll
      for (int off = 1; off < 32; off <<= 1) {
        unsigned long long q2 = __shfl_xor(q, off);
        q = q2 < q ? q2 : q;
      }
      if (code32 == 0) atomicMin(&pk[pidx[px]], q);
    }
  }
}

__global__ __launch_bounds__(256) void k_gather(const float* __restrict__ ze,
                                                const float* __restrict__ cb,
                                                const unsigned long long* __restrict__ pk,
                                                float* __restrict__ out_zq,
                                                float* __restrict__ out_idx,
                                                float* __restrict__ part) {
  __shared__ float qrow[64][257];
  __shared__ int sidx[64];
  int tid = threadIdx.x;
  int p0 = blockIdx.x * 64;
  int b = p0 >> 10, hw0 = p0 & 1023;
  if (tid < 64) {
    int bi = (int)(unsigned int)(pk[p0 + tid] & 0xffffffffull);
    sidx[tid] = bi;
    out_idx[p0 + tid] = (float)bi;
  }
  __syncthreads();
  for (int r = 0; r < 64; ++r)
    qrow[r][tid] = cb[(size_t)sidx[r] * 256 + tid];
  __syncthreads();
  float lsum = 0.f;
  size_t zbase = (size_t)b * 262144 + hw0;
#pragma unroll 4
  for (int i = 0; i < 64; ++i) {
    int px = tid & 63;
    int c = i * 4 + (tid >> 6);
    float qv = qrow[px][c];
    size_t gi = zbase + (size_t)c * 1024 + px;
    float zev = ze[gi];
    out_zq[gi] = __fadd_rn(zev, __fsub_rn(qv, zev));
    float d = zev - qv;
    lsum = __builtin_fmaf(d, d, lsum);
  }
#pragma unroll
  for (int off = 32; off; off >>= 1) lsum += __shfl_xor(lsum, off, 64);
  __shared__ float wsum[4];
  if ((tid & 63) == 0) wsum[tid >> 6] = lsum;
  __syncthreads();
  if (tid == 0) part[blockIdx.x] = (wsum[0] + wsum[1]) + (wsum[2] + wsum[3]);
}

__global__ __launch_bounds__(256) void k_final(const float* __restrict__ part,
                                               float* __restrict__ out0) {
  int tid = threadIdx.x;
  float s = part[tid];
#pragma unroll
  for (int off = 32; off; off >>= 1) s += __shfl_xor(s, off, 64);
  __shared__ float wsum[4];
  if ((tid & 63) == 0) wsum[tid >> 6] = s;
  __syncthreads();
  if (tid == 0)
    out0[0] = 1.25f * ((wsum[0] + wsum[1]) + (wsum[2] + wsum[3])) / 4194304.0f;
}

extern "C" void kernel_launch(void* const* d_in, const int* in_sizes, int n_in,
                              void* d_out, int out_size, void* d_ws, size_t ws_size,
                              hipStream_t stream) {
  const float* ze = (const float*)d_in[0];
  const float* cb = (const float*)d_in[1];
  float* out = (float*)d_out;
  char* ws = (char*)d_ws;
  short* zebff = (short*)(ws + WS_ZEBF);
  short* cbbft = (short*)(ws + WS_CBBF);
  float* zef = (float*)(ws + WS_ZEF);
  float* bn = (float*)(ws + WS_BN);
  float* an = (float*)(ws + WS_AN);
  float* wsmin = (float*)(ws + WS_MIN);
  float* cbsw = (float*)(ws + WS_MIN);  // alias: wsmin dead after k_compact
  float* tau = (float*)(ws + WS_TAU);
  int* blist = (int*)(ws + WS_BLIST);
  int* bcnt = (int*)(ws + WS_BCNT);
  unsigned* bmaxu = (unsigned*)(ws + WS_BMAXU);
  int* qcnt = (int*)(ws + WS_QCNT);
  int* queue = (int*)(ws + WS_QUEUE);
  unsigned long long* pk = (unsigned long long*)(ws + WS_PK);
  float* part = (float*)(ws + WS_PART);
  float* out_loss = out;
  float* out_zq = out + 1;
  float* out_idx = out + 1 + 4194304;

  k_cvt_ze<<<256, 256, 0, stream>>>(ze, zebff, zef, an, bmaxu, qcnt);
  k_cvt_cb<<<128, 256, 0, stream>>>(cb, cbbft, bn, bmaxu);
  k_gemm<<<1024, 256, 0, stream>>>(zebff, cbbft, bn, wsmin);
  k_tau<<<256, 256, 0, stream>>>(wsmin, an, bmaxu, tau, pk);
  k_compact<<<128, 256, 0, stream>>>(wsmin, tau, cb, cbsw, bcnt, blist, qcnt,
                                     queue);
  k_rescore_b<<<512, 256, 0, stream>>>(zef, cbsw, an, bn, bcnt, blist, qcnt,
                                       queue, pk);
  k_gather<<<256, 256, 0, stream>>>(ze, cb, pk, out_zq, out_idx, part);
  k_final<<<1, 256, 0, stream>>>(part, out_loss);
}

// Round 20
// 170.171 us; speedup vs baseline: 1.7675x; 1.7675x over previous
//
#include <hip/hip_runtime.h>
#include <hip/hip_bf16.h>

#define NPIX 16384
#define NVOC 8192
#define CHUNK 32

typedef short short8v __attribute__((ext_vector_type(8)));
typedef float floatx4 __attribute__((ext_vector_type(4)));

// ---- ws layout (bytes) ----
// region A (0..8 MB): zebf(frag) during cvt/gemm -> blist after gemm -> part
#define WS_ZEBF   0u          // 16384*256 bf16 = 8388608 (dead after k_gemm)
#define WS_BLIST  0u          // 128*16384 i32 = 8388608 (alias, post-gemm)
#define WS_PART   0u          // 256 f32 (alias, post-rescore; blist dead)
// region B: cbbft during gemm -> pk/tau after gemm
#define WS_CBBF   8388608u    // 8192*256 bf16 = 4194304 (dead after k_gemm)
#define WS_PK     8388608u    // 16384 u64 = 131072 (alias, post-gemm)
#define WS_TAU    8519680u    // 16384 f32 = 65536 (alias, post-gemm)
// persistent (wsmin dead after k_compact -> overwritten with swizzled cb fp32)
#define WS_ZEF    12582912u   // 16384*256 f32 = 16777216
#define WS_MIN    29360128u   // 128*16384 f32 = 8388608 ; cbsw after compact
#define WS_BN     37748736u   // 8192 f32
#define WS_AN     37781504u   // 16384 f32
#define WS_BCNT   37847040u   // 128 i32 (pad to 512)
#define WS_BMAXU  37847552u   // 1 u32
#define WS_QCNT   37847556u   // 1 i32
#define WS_QUEUE  37847808u   // 131072 i32 = 524288 (max need 128*512*2)

__device__ __forceinline__ short f2bf(float v) {
  __bf16 h = (__bf16)v;
  return __builtin_bit_cast(short, h);
}

__device__ __forceinline__ unsigned long long packdj(float d, int j) {
  return ((unsigned long long)__float_as_uint(d) << 32) | (unsigned int)j;
}

__device__ __forceinline__ void gll16(const void* g, void* l) {
  __builtin_amdgcn_global_load_lds(
      (const __attribute__((address_space(1))) void*)g,
      (__attribute__((address_space(3))) void*)l, 16, 0, 0);
}

// numpy pairwise-sum of 128 squares
__device__ __forceinline__ float np_pairwise128_sq(const float* x, int stride) {
  float r[8];
#pragma unroll
  for (int j = 0; j < 8; ++j) {
    float v = x[j * stride];
    r[j] = __fmul_rn(v, v);
  }
#pragma unroll
  for (int i = 1; i < 16; ++i) {
#pragma unroll
    for (int j = 0; j < 8; ++j) {
      float v = x[(i * 8 + j) * stride];
      r[j] = __fadd_rn(r[j], __fmul_rn(v, v));
    }
  }
  return __fadd_rn(__fadd_rn(__fadd_rn(r[0], r[1]), __fadd_rn(r[2], r[3])),
                   __fadd_rn(__fadd_rn(r[4], r[5]), __fadd_rn(r[6], r[7])));
}

// ze [16][256][1024] fp32 -> zebf in MFMA-FRAGMENT order + zef (fp32) + an.
// Also inits bmaxu/qcnt (runs first).
__global__ __launch_bounds__(256) void k_cvt_ze(const float* __restrict__ ze,
                                                short* __restrict__ zebff,
                                                float* __restrict__ zef,
                                                float* __restrict__ an,
                                                unsigned* __restrict__ bmaxu,
                                                int* __restrict__ qcnt) {
  __shared__ float t[64][132];
  int tid = threadIdx.x;
  if (blockIdx.x == 0 && tid == 0) {
    bmaxu[0] = 0u;
    qcnt[0] = 0;
  }
  int p0 = blockIdx.x * 64;
  int b = p0 >> 10, hw0 = p0 & 1023;
  const float* src = ze + (size_t)b * 262144 + hw0;
  float apart = 0.f;
  for (int half = 0; half < 2; ++half) {
    if (half) __syncthreads();
    {
      int hw = tid & 63, cq = tid >> 6;
#pragma unroll
      for (int i = 0; i < 32; ++i) {
        int cl = i * 4 + cq;
        t[hw][cl] = src[(size_t)(half * 128 + cl) * 1024 + hw];
      }
    }
    __syncthreads();
    {
      int r = tid >> 2, cg = tid & 3;
      float* fd = zef + (size_t)(p0 + r) * 256 + half * 128 + cg * 32;
#pragma unroll
      for (int s = 0; s < 8; ++s) {
        float4 v = *reinterpret_cast<const float4*>(&t[r][cg * 32 + s * 4]);
        *reinterpret_cast<float4*>(fd + s * 4) = v;
      }
    }
    {
      int pg_l = tid >> 6, l = tid & 63;
      size_t pg = (size_t)(p0 >> 4) + pg_l;
      int lr = l & 15, lg = l >> 4;
#pragma unroll
      for (int kl = 0; kl < 4; ++kl) {
        int ks = half * 4 + kl;
        short8v v8;
#pragma unroll
        for (int e = 0; e < 8; ++e)
          v8[e] = f2bf(t[pg_l * 16 + lr][kl * 32 + lg * 8 + e]);
        *reinterpret_cast<short8v*>(zebff + (pg * 8 + ks) * 512 + l * 8) = v8;
      }
    }
    if (tid < 64) {
      float a = np_pairwise128_sq(&t[tid][0], 1);
      apart = half ? __fadd_rn(apart, a) : a;
    }
  }
  if (tid < 64) an[p0 + tid] = apart;
}

// FUSED: cb -> bf16 per-tile K-MAJOR layout + bn (numpy-order, bit-identical,
// from the same fp32 LDS staging) + bmax atomic. One 8.4MB read instead of two.
__global__ __launch_bounds__(256) void k_cvt_cb(const float* __restrict__ cb,
                                                short* __restrict__ cbbft,
                                                float* __restrict__ bn,
                                                unsigned* __restrict__ bmaxu) {
  __shared__ float rows[64][257];
  int tid = threadIdx.x;
  int j0 = blockIdx.x * 64;
  for (int r = 0; r < 64; ++r)
    rows[r][tid] = cb[(size_t)(j0 + r) * 256 + tid];
  __syncthreads();
  if (tid < 64) {
    float a = np_pairwise128_sq(&rows[tid][0], 1);
    float b2 = np_pairwise128_sq(&rows[tid][128], 1);
    float v = __fadd_rn(a, b2);
    bn[j0 + tid] = v;
    atomicMax(bmaxu, __float_as_uint(v));
  }
  short* dst = cbbft + (size_t)blockIdx.x * 16384;
#pragma unroll
  for (int s = 0; s < 8; ++s) {
    int cid = tid + s * 256;
    int kc = cid >> 6, c2 = cid & 63;
    short8v v;
#pragma unroll
    for (int e = 0; e < 8; ++e) v[e] = f2bf(rows[c2][kc * 8 + e]);
    *reinterpret_cast<short8v*>(dst + cid * 8) = v;
  }
}

// Swapped-operand bf16 MFMA distance GEMM, 2 blocks/CU (R15/R18 proven 62.6us).
__global__ __launch_bounds__(256, 2) void k_gemm(const short* __restrict__ zebff,
                                                 const short* __restrict__ cbbft,
                                                 const float* __restrict__ bn,
                                                 float* __restrict__ wsmin) {
  __shared__ short lds[32768];   // 2 x 32 KB B-tile buffers
  __shared__ float bnlds[1024];  // octant bn
  int tid = threadIdx.x;
  int lane = tid & 63, w = tid >> 6;
  int g = lane >> 4, r16 = lane & 15;
  int oct = blockIdx.x & 7, chunk = blockIdx.x >> 3;
  int p0 = chunk * 256;
  int ncol0 = oct * 1024;

  short8v pix[4][8];
  {
    const short* base = zebff + ((size_t)(p0 >> 4) + w * 4) * 4096 + lane * 8;
#pragma unroll
    for (int pf = 0; pf < 4; ++pf)
#pragma unroll
      for (int ks = 0; ks < 8; ++ks)
        pix[pf][ks] =
            *reinterpret_cast<const short8v*>(base + pf * 4096 + ks * 512);
  }
  gll16(bn + ncol0 + tid * 4, &bnlds[tid * 4]);

#define STAGE(t, boff)                                                         \
  {                                                                            \
    const short* src_ = cbbft + (size_t)(oct * 16 + (t)) * 16384;              \
    _Pragma("unroll") for (int s = 0; s < 8; ++s) {                            \
      int cid_ = tid + s * 256;                                                \
      gll16(src_ + cid_ * 8, &lds[(boff) + cid_ * 8]);                         \
    }                                                                          \
  }
  STAGE(0, 0)
  asm volatile("s_waitcnt vmcnt(0)" ::: "memory");
  __builtin_amdgcn_s_barrier();

  float* wbase = wsmin + (size_t)(oct * 16) * NPIX + p0 + w * 64 + r16;

  for (int t = 0; t < 16; ++t) {
    int bA = (t & 1) * 16384;
    int bC = bA ^ 16384;
    if (t < 15) STAGE(t + 1, bC)
    float4 bnv[4];
#pragma unroll
    for (int cf = 0; cf < 4; ++cf)
      bnv[cf] =
          *reinterpret_cast<const float4*>(&bnlds[t * 64 + cf * 16 + g * 4]);
    floatx4 acc[4][4];
#pragma unroll
    for (int cf = 0; cf < 4; ++cf)
#pragma unroll
      for (int pf = 0; pf < 4; ++pf) acc[cf][pf] = floatx4{0.f, 0.f, 0.f, 0.f};
    __builtin_amdgcn_s_setprio(1);
#pragma unroll
    for (int ks = 0; ks < 8; ++ks) {  // k-ascending: bit-identical chains
      short8v cfr[4];
#pragma unroll
      for (int cf = 0; cf < 4; ++cf)
        cfr[cf] = *reinterpret_cast<const short8v*>(
            &lds[bA + (((ks * 4 + g) * 64) + cf * 16 + r16) * 8]);
#pragma unroll
      for (int cf = 0; cf < 4; ++cf)
#pragma unroll
        for (int pf = 0; pf < 4; ++pf)
          acc[cf][pf] = __builtin_amdgcn_mfma_f32_16x16x32_bf16(
              cfr[cf], pix[pf][ks], acc[cf][pf], 0, 0, 0);
    }
    __builtin_amdgcn_s_setprio(0);
    float pmin[4];
#pragma unroll
    for (int pf = 0; pf < 4; ++pf) {
      float m_ = 3.4e38f;
#pragma unroll
      for (int cf = 0; cf < 4; ++cf) {
        m_ = fminf(m_, __builtin_fmaf(-2.0f, acc[cf][pf][0], bnv[cf].x));
        m_ = fminf(m_, __builtin_fmaf(-2.0f, acc[cf][pf][1], bnv[cf].y));
        m_ = fminf(m_, __builtin_fmaf(-2.0f, acc[cf][pf][2], bnv[cf].z));
        m_ = fminf(m_, __builtin_fmaf(-2.0f, acc[cf][pf][3], bnv[cf].w));
      }
      m_ = fminf(m_, __shfl_xor(m_, 16));
      m_ = fminf(m_, __shfl_xor(m_, 32));
      pmin[pf] = m_;
    }
    if (lane < 16) {
#pragma unroll
      for (int pf = 0; pf < 4; ++pf)
        wbase[(size_t)t * NPIX + pf * 16] = pmin[pf];
    }
    if (t < 15) asm volatile("s_waitcnt vmcnt(4)" ::: "memory");
    __builtin_amdgcn_s_barrier();
  }
#undef STAGE
}

// per-pixel global min over 128 colblocks -> tau; init pk. No atomics.
__global__ __launch_bounds__(256) void k_tau(const float* __restrict__ wsmin,
                                             const float* __restrict__ an,
                                             const unsigned* __restrict__ bmaxu,
                                             float* __restrict__ tau,
                                             unsigned long long* __restrict__ pk) {
  __shared__ float sm[4][64];
  int tid = threadIdx.x;
  int px = tid & 63, q = tid >> 6;
  int p = blockIdx.x * 64 + px;
  float m0 = 3.4e38f, m1 = 3.4e38f, m2 = 3.4e38f, m3 = 3.4e38f;
#pragma unroll
  for (int i = 0; i < 8; ++i) {
    int c = q * 32 + i * 4;
    m0 = fminf(m0, wsmin[(size_t)c * NPIX + p]);
    m1 = fminf(m1, wsmin[(size_t)(c + 1) * NPIX + p]);
    m2 = fminf(m2, wsmin[(size_t)(c + 2) * NPIX + p]);
    m3 = fminf(m3, wsmin[(size_t)(c + 3) * NPIX + p]);
  }
  sm[q][px] = fminf(fminf(m0, m1), fminf(m2, m3));
  __syncthreads();
  if (tid < 64) {
    float m = fminf(fminf(sm[0][tid], sm[1][tid]), fminf(sm[2][tid], sm[3][tid]));
    float bmaxf = sqrtf(__uint_as_float(bmaxu[0]));
    tau[p] = m + 0.017f * sqrtf(an[p]) * bmaxf + 2e-4f;
    pk[p] = ~0ull;
  }
}

// per-colblock compaction of flagged pixels (ascending p, zero contention);
// emits 32-code-group descriptors; then overwrites its own (now dead) wsmin
// row with the swizzled fp32 codebook rows 64c..64c+63 (cbsw) — fused k_swz.
__global__ __launch_bounds__(256) void k_compact(const float* __restrict__ wsmin,
                                                 const float* __restrict__ tau,
                                                 const float* __restrict__ cb,
                                                 float* __restrict__ cbsw,
                                                 int* __restrict__ bcnt,
                                                 int* __restrict__ blist,
                                                 int* __restrict__ qcnt,
                                                 int* __restrict__ queue) {
  __shared__ int wbase[4];
  __shared__ int running;
  int c = blockIdx.x;
  const float* row = wsmin + (size_t)c * NPIX;
  int* dst = blist + (size_t)c * NPIX;
  int tid = threadIdx.x;
  int lane = tid & 63, wv = tid >> 6;
  if (tid == 0) running = 0;
  __syncthreads();
  for (int base = 0; base < NPIX; base += 256) {
    int p = base + tid;
    bool flag = row[p] <= tau[p];
    unsigned long long mask = __ballot(flag);
    int cnt = __popcll(mask);
    int pre = __popcll(mask & ((1ull << lane) - 1ull));
    if (lane == 0) wbase[wv] = cnt;
    __syncthreads();
    if (tid == 0) {
      int r = running;
#pragma unroll
      for (int w2 = 0; w2 < 4; ++w2) {
        int t = wbase[w2];
        wbase[w2] = r;
        r += t;
      }
      running = r;
    }
    __syncthreads();
    if (flag) dst[wbase[wv] + pre] = p;
    __syncthreads();
  }
  if (tid == 0) {
    int n = running;
    bcnt[c] = n;
    int nch = (n + CHUNK - 1) / CHUNK;
    if (nch > 0) {
      int q0 = atomicAdd(qcnt, nch * 2);
      for (int i = 0; i < nch; ++i) {
        queue[q0 + 2 * i] = (2 * c) | (i << 16);
        queue[q0 + 2 * i + 1] = (2 * c + 1) | (i << 16);
      }
    }
  }
  {
    const float4* cb4 = reinterpret_cast<const float4*>(cb);
    float4* dst4 = reinterpret_cast<float4*>(cbsw);
#pragma unroll
    for (int i = 0; i < 16; ++i) {
      int gid = tid + i * 256;
      int jj = 64 * c + (gid >> 6), u = gid & 63;
      dst4[(size_t)jj * 64 + u] = cb4[(size_t)jj * 64 + (u ^ (jj & 7))];
    }
  }
}

// queue-driven exact fp32 rescore v5: 2 blocks/CU (LDS 64.3KB). (unchanged)
__global__ __launch_bounds__(256, 2) void k_rescore_b(
    const float* __restrict__ zef, const float* __restrict__ cbsw,
    const float* __restrict__ an, const float* __restrict__ bn,
    const int* __restrict__ bcnt, const int* __restrict__ blist,
    const int* __restrict__ qcnt, const int* __restrict__ queue,
    unsigned long long* __restrict__ pk) {
  __shared__ float zl[32 * 256];
  __shared__ float cstf[32 * 256];
  __shared__ int pidx[32];
  __shared__ float apx[32];
  int tid = threadIdx.x;
  int lane = tid & 63, wv = tid >> 6;
  int code32 = lane & 31, half = lane >> 5;
  int nq = qcnt[0];
  for (int qi = blockIdx.x; qi < nq; qi += 512) {
    int e = queue[qi];
    int g = e & 0xffff, chunk = e >> 16;
    int c = g >> 1;
    int n = bcnt[c];
    int base = chunk * CHUNK;
    int cnt_here = min(CHUNK, n - base);
    __syncthreads();  // WAR vs previous entry's readers
#pragma unroll
    for (int i = 0; i < 8; ++i) {
      int px = wv * 8 + i;
      int idx = base + min(px, cnt_here - 1);
      int p = blist[(size_t)c * NPIX + idx];
      gll16(zef + (size_t)p * 256 + lane * 4, &zl[px * 256 + lane * 4]);
    }
#pragma unroll
    for (int i = 0; i < 8; ++i) {
      int r = wv * 8 + i;
      gll16(cbsw + (size_t)(g * 32 + r) * 256 + lane * 4,
            &cstf[r * 256 + lane * 4]);
    }
    if (tid < 32) {
      int idx = base + min(tid, cnt_here - 1);
      int p = blist[(size_t)c * NPIX + idx];
      pidx[tid] = p;
      apx[tid] = an[p];
    }
    asm volatile("s_waitcnt vmcnt(0)" ::: "memory");
    __syncthreads();
    int jg = g * 32 + code32;
    float bnj = bn[jg];
    int px0 = wv * 8 + half * 4;
    int sw = code32 & 7;
    const float* crow = &cstf[code32 * 256];
    float acc[4] = {0.f, 0.f, 0.f, 0.f};
#pragma unroll 8
    for (int k4 = 0; k4 < 64; ++k4) {
      float4 cv = *reinterpret_cast<const float4*>(&crow[(k4 ^ sw) << 2]);
#pragma unroll
      for (int i = 0; i < 4; ++i) {
        float4 zv =
            *reinterpret_cast<const float4*>(&zl[(px0 + i) * 256 + k4 * 4]);
        acc[i] = __builtin_fmaf(zv.x, cv.x, acc[i]);
        acc[i] = __builtin_fmaf(zv.y, cv.y, acc[i]);
        acc[i] = __builtin_fmaf(zv.z, cv.z, acc[i]);
        acc[i] = __builtin_fmaf(zv.w, cv.w, acc[i]);
      }
    }
#pragma unroll
    for (int i = 0; i < 4; ++i) {
      int px = px0 + i;
      float d = __fsub_rn(__fadd_rn(apx[px], bnj), 2.0f * acc[i]);
      unsigned long long q = packdj(d, jg);
#pragma unroll
      for (int off = 1; off < 32; off <<= 1) {
        unsigned long long q2 = __shfl_xor(q, off);
        q = q2 < q ? q2 : q;
      }
      if (code32 == 0) atomicMin(&pk[pidx[px]], q);
    }
  }
}

__global__ __launch_bounds__(256) void k_gather(const float* __restrict__ ze,
                                                const float* __restrict__ cb,
                                                const unsigned long long* __restrict__ pk,
                                                float* __restrict__ out_zq,
                                                float* __restrict__ out_idx,
                                                float* __restrict__ part) {
  __shared__ float qrow[64][257];
  __shared__ int sidx[64];
  int tid = threadIdx.x;
  int p0 = blockIdx.x * 64;
  int b = p0 >> 10, hw0 = p0 & 1023;
  if (tid < 64) {
    int bi = (int)(unsigned int)(pk[p0 + tid] & 0xffffffffull);
    sidx[tid] = bi;
    out_idx[p0 + tid] = (float)bi;
  }
  __syncthreads();
  for (int r = 0; r < 64; ++r)
    qrow[r][tid] = cb[(size_t)sidx[r] * 256 + tid];
  __syncthreads();
  float lsum = 0.f;
  size_t zbase = (size_t)b * 262144 + hw0;
#pragma unroll 4
  for (int i = 0; i < 64; ++i) {
    int px = tid & 63;
    int c = i * 4 + (tid >> 6);
    float qv = qrow[px][c];
    size_t gi = zbase + (size_t)c * 1024 + px;
    float zev = ze[gi];
    out_zq[gi] = __fadd_rn(zev, __fsub_rn(qv, zev));
    float d = zev - qv;
    lsum = __builtin_fmaf(d, d, lsum);
  }
#pragma unroll
  for (int off = 32; off; off >>= 1) lsum += __shfl_xor(lsum, off, 64);
  __shared__ float wsum[4];
  if ((tid & 63) == 0) wsum[tid >> 6] = lsum;
  __syncthreads();
  if (tid == 0) part[blockIdx.x] = (wsum[0] + wsum[1]) + (wsum[2] + wsum[3]);
}

__global__ __launch_bounds__(256) void k_final(const float* __restrict__ part,
                                               float* __restrict__ out0) {
  int tid = threadIdx.x;
  float s = part[tid];
#pragma unroll
  for (int off = 32; off; off >>= 1) s += __shfl_xor(s, off, 64);
  __shared__ float wsum[4];
  if ((tid & 63) == 0) wsum[tid >> 6] = s;
  __syncthreads();
  if (tid == 0)
    out0[0] = 1.25f * ((wsum[0] + wsum[1]) + (wsum[2] + wsum[3])) / 4194304.0f;
}

extern "C" void kernel_launch(void* const* d_in, const int* in_sizes, int n_in,
                              void* d_out, int out_size, void* d_ws, size_t ws_size,
                              hipStream_t stream) {
  const float* ze = (const float*)d_in[0];
  const float* cb = (const float*)d_in[1];
  float* out = (float*)d_out;
  char* ws = (char*)d_ws;
  short* zebff = (short*)(ws + WS_ZEBF);
  short* cbbft = (short*)(ws + WS_CBBF);
  float* zef = (float*)(ws + WS_ZEF);
  float* bn = (float*)(ws + WS_BN);
  float* an = (float*)(ws + WS_AN);
  float* wsmin = (float*)(ws + WS_MIN);
  float* cbsw = (float*)(ws + WS_MIN);  // alias: wsmin dead after k_compact
  float* tau = (float*)(ws + WS_TAU);
  int* blist = (int*)(ws + WS_BLIST);
  int* bcnt = (int*)(ws + WS_BCNT);
  unsigned* bmaxu = (unsigned*)(ws + WS_BMAXU);
  int* qcnt = (int*)(ws + WS_QCNT);
  int* queue = (int*)(ws + WS_QUEUE);
  unsigned long long* pk = (unsigned long long*)(ws + WS_PK);
  float* part = (float*)(ws + WS_PART);
  float* out_loss = out;
  float* out_zq = out + 1;
  float* out_idx = out + 1 + 4194304;

  k_cvt_ze<<<256, 256, 0, stream>>>(ze, zebff, zef, an, bmaxu, qcnt);
  k_cvt_cb<<<128, 256, 0, stream>>>(cb, cbbft, bn, bmaxu);
  k_gemm<<<512, 256, 0, stream>>>(zebff, cbbft, bn, wsmin);
  k_tau<<<256, 256, 0, stream>>>(wsmin, an, bmaxu, tau, pk);
  k_compact<<<128, 256, 0, stream>>>(wsmin, tau, cb, cbsw, bcnt, blist, qcnt,
                                     queue);
  k_rescore_b<<<512, 256, 0, stream>>>(zef, cbsw, an, bn, bcnt, blist, qcnt,
                                       queue, pk);
  k_gather<<<256, 256, 0, stream>>>(ze, cb, pk, out_zq, out_idx, part);
  k_final<<<1, 256, 0, stream>>>(part, out_loss);
}